// Round 1
// baseline (283.672 us; speedup 1.0000x reference)
//
#include <hip/hip_runtime.h>
#include <hip/hip_bf16.h>
#include <cstdint>

#define B_ROWS 16384
#define NCLS 1000
#define NPAD 1024
#define FDIM 768
#define TEMP_INV 10.0f

typedef float floatx4 __attribute__((ext_vector_type(4)));
typedef short short8 __attribute__((ext_vector_type(8)));
typedef unsigned short ushort8v __attribute__((ext_vector_type(8)));

__device__ inline unsigned short f2bf(float f) {
  unsigned int u = __float_as_uint(f);
  u += 0x7FFFu + ((u >> 16) & 1u);   // round-to-nearest-even
  return (unsigned short)(u >> 16);
}

// ---------------- Kernel E: convert centers fp32 -> bf16, zero-pad rows 1000..1023
__global__ void cvt_centers_kernel(const float* __restrict__ centers,
                                   unsigned short* __restrict__ cbf) {
  int i = blockIdx.x * 256 + threadIdx.x;   // grid covers NPAD*FDIM
  float v = 0.0f;
  if (i < NCLS * FDIM) v = centers[i];
  cbf[i] = f2bf(v);
}

// ---------------- Kernel A: CE partials. One wave per row, 4 rows/block.
__global__ __launch_bounds__(256) void ce_kernel(const float* __restrict__ outputs,
                                                 const int* __restrict__ labels,
                                                 float* __restrict__ ce_partial) {
  __shared__ float ared[4];
  const int wid = threadIdx.x >> 6;
  const int lane = threadIdx.x & 63;
  const int b = blockIdx.x * 4 + wid;
  const float* row = outputs + (size_t)b * NCLS;
  const float4* r4 = reinterpret_cast<const float4*>(row);
  float4 v[4];
  float m = -1e30f;
#pragma unroll
  for (int it = 0; it < 4; ++it) {
    int idx = lane + it * 64;
    if (idx < 250) v[it] = r4[idx];
    else { v[it].x = -1e30f; v[it].y = -1e30f; v[it].z = -1e30f; v[it].w = -1e30f; }
    m = fmaxf(m, fmaxf(fmaxf(v[it].x, v[it].y), fmaxf(v[it].z, v[it].w)));
  }
#pragma unroll
  for (int msk = 1; msk < 64; msk <<= 1) m = fmaxf(m, __shfl_xor(m, msk));
  float s = 0.f;
#pragma unroll
  for (int it = 0; it < 4; ++it)
    s += __expf(v[it].x - m) + __expf(v[it].y - m) + __expf(v[it].z - m) + __expf(v[it].w - m);
#pragma unroll
  for (int msk = 1; msk < 64; msk <<= 1) s += __shfl_xor(s, msk);
  if (lane == 0) {
    float lse = m + logf(s);
    ared[wid] = lse - row[labels[b]];
  }
  __syncthreads();
  if (threadIdx.x == 0)
    ce_partial[blockIdx.x] = ared[0] + ared[1] + ared[2] + ared[3];
}

// ---------------- Kernel B: fused sims GEMM (bf16 MFMA) + online softmax stats.
// Block = 256 thr (4 waves), 32 rows. A-tile (32x768 bf16) fully LDS-resident.
// 8 column sweeps of 128 (N padded to 1024, masked >=1000). Wave tile 32x32.
__global__ __launch_bounds__(256, 2) void sims_kernel(
    const float* __restrict__ features,
    const unsigned short* __restrict__ cbf,
    const int* __restrict__ labels,
    float* __restrict__ p_true,
    float* __restrict__ sdc_partial) {
  __shared__ unsigned short As[32 * 776];   // 768 + 8 pad: 2-way-max bank pattern
  __shared__ unsigned short Bs[128 * 40];   // 32 + 8 pad
  __shared__ float stat_m[32][4];
  __shared__ float stat_s[32][4];
  __shared__ float ztrue[32];
  __shared__ int lab[32];
  __shared__ float red[32];

  const int t = threadIdx.x;
  const int rb0 = blockIdx.x * 32;
  const int w = t >> 6;          // wave 0..3 -> col-group
  const int lane = t & 63;
  const int quad = lane >> 4;
  const int l15 = lane & 15;

  if (t < 32) {
    lab[t] = labels[rb0 + t];
#pragma unroll
    for (int g = 0; g < 4; ++g) { stat_m[t][g] = -1e30f; stat_s[t][g] = 0.f; }
  }

  // stage A: 32 rows x 768 k, fp32 -> bf16
  {
    const float4* f4 = reinterpret_cast<const float4*>(features + (size_t)rb0 * FDIM);
    for (int it = 0; it < 24; ++it) {
      int i = t + 256 * it;              // 0..6143 float4s, contiguous
      int row = i / 192;
      int c4 = i - row * 192;
      float4 v = f4[i];
      ushort4 o;
      o.x = f2bf(v.x); o.y = f2bf(v.y); o.z = f2bf(v.z); o.w = f2bf(v.w);
      *reinterpret_cast<ushort4*>(&As[row * 776 + c4 * 4]) = o;
    }
  }
  __syncthreads();

  for (int ct = 0; ct < 8; ++ct) {
    floatx4 acc00 = {0.f, 0.f, 0.f, 0.f};
    floatx4 acc01 = acc00, acc10 = acc00, acc11 = acc00;
    for (int ks = 0; ks < 24; ++ks) {
      // stage B tile: 128 center-rows x 32 k (bf16), 512 x 16B chunks
#pragma unroll
      for (int rr = 0; rr < 2; ++rr) {
        int cidx = t + 256 * rr;
        int brow = cidx >> 2, ch = cidx & 3;
        ushort8v v = *reinterpret_cast<const ushort8v*>(
            cbf + (size_t)(ct * 128 + brow) * FDIM + ks * 32 + ch * 8);
        *reinterpret_cast<ushort8v*>(&Bs[brow * 40 + ch * 8]) = v;
      }
      __syncthreads();
      short8 a0 = *reinterpret_cast<const short8*>(&As[l15 * 776 + ks * 32 + quad * 8]);
      short8 a1 = *reinterpret_cast<const short8*>(&As[(16 + l15) * 776 + ks * 32 + quad * 8]);
      short8 b0 = *reinterpret_cast<const short8*>(&Bs[(w * 32 + l15) * 40 + quad * 8]);
      short8 b1 = *reinterpret_cast<const short8*>(&Bs[(w * 32 + 16 + l15) * 40 + quad * 8]);
      acc00 = __builtin_amdgcn_mfma_f32_16x16x32_bf16(a0, b0, acc00, 0, 0, 0);
      acc01 = __builtin_amdgcn_mfma_f32_16x16x32_bf16(a0, b1, acc01, 0, 0, 0);
      acc10 = __builtin_amdgcn_mfma_f32_16x16x32_bf16(a1, b0, acc10, 0, 0, 0);
      acc11 = __builtin_amdgcn_mfma_f32_16x16x32_bf16(a1, b1, acc11, 0, 0, 0);
      __syncthreads();
    }
    // online-softmax stats for this wave's 32 cols
    int cb = ct * 128 + w * 32;
#pragma unroll
    for (int fr = 0; fr < 2; ++fr) {
#pragma unroll
      for (int r = 0; r < 4; ++r) {
        float z0 = (fr == 0 ? acc00[r] : acc10[r]) * TEMP_INV;
        float z1 = (fr == 0 ? acc01[r] : acc11[r]) * TEMP_INV;
        int rowl = fr * 16 + quad * 4 + r;
        int c0 = cb + l15;
        int c1 = cb + 16 + l15;
        int lb = lab[rowl];
        if (c0 == lb) ztrue[rowl] = z0;
        if (c1 == lb) ztrue[rowl] = z1;
        if (c0 >= NCLS) z0 = -1e30f;
        if (c1 >= NCLS) z1 = -1e30f;
        float m = fmaxf(z0, z1);
#pragma unroll
        for (int msk = 1; msk < 16; msk <<= 1) m = fmaxf(m, __shfl_xor(m, msk));
        float s = __expf(z0 - m) + __expf(z1 - m);
#pragma unroll
        for (int msk = 1; msk < 16; msk <<= 1) s += __shfl_xor(s, msk);
        if (l15 == 0) {
          float mo = stat_m[rowl][w], so = stat_s[rowl][w];
          float mn = fmaxf(mo, m);
          stat_s[rowl][w] = so * __expf(mo - mn) + s * __expf(m - mn);
          stat_m[rowl][w] = mn;
        }
      }
    }
  }
  __syncthreads();
  if (t < 32) {
    float mn = fmaxf(fmaxf(stat_m[t][0], stat_m[t][1]), fmaxf(stat_m[t][2], stat_m[t][3]));
    float S = stat_s[t][0] * __expf(stat_m[t][0] - mn)
            + stat_s[t][1] * __expf(stat_m[t][1] - mn)
            + stat_s[t][2] * __expf(stat_m[t][2] - mn)
            + stat_s[t][3] * __expf(stat_m[t][3] - mn);
    float p = __expf(ztrue[t] - mn) / S;
    p_true[rb0 + t] = p;
    red[t] = -logf(p + 1e-8f);
  }
  __syncthreads();
  if (t == 0) {
    float s = 0.f;
#pragma unroll
    for (int i = 0; i < 32; ++i) s += red[i];
    sdc_partial[blockIdx.x] = s;
  }
}

// ---------------- Kernel C: M-step, one block per class.
__global__ __launch_bounds__(256) void mstep_kernel(
    const float* __restrict__ features,
    const float* __restrict__ centers,
    const int* __restrict__ labels,
    const float* __restrict__ p_true,
    float* __restrict__ out_centers) {
  __shared__ int idxs[2048];
  __shared__ float ps[2048];
  __shared__ int cnt;
  const int c = blockIdx.x;
  const int t = threadIdx.x;
  float acc0 = 0.f, acc1 = 0.f, acc2 = 0.f, wsum = 0.f;
  for (int chunk = 0; chunk < B_ROWS; chunk += 2048) {
    if (t == 0) cnt = 0;
    __syncthreads();
    for (int j = t; j < 2048; j += 256) {
      int b = chunk + j;
      if (labels[b] == c) {
        int k = atomicAdd(&cnt, 1);
        idxs[k] = b;
        ps[k] = p_true[b];
      }
    }
    __syncthreads();
    int n = cnt;
    for (int j = 0; j < n; ++j) {
      int b = idxs[j];
      float p = ps[j];
      const float* f = features + (size_t)b * FDIM;
      acc0 += p * f[t];
      acc1 += p * f[t + 256];
      acc2 += p * f[t + 512];
      wsum += p;
    }
    __syncthreads();
  }
  const float* crow = centers + (size_t)c * FDIM;
  float c0 = crow[t], c1 = crow[t + 256], c2 = crow[t + 512];
  size_t o = (size_t)c * FDIM + t;
  if (wsum > 0.f) {
    float inv = 0.1f / (wsum + 1e-8f);
    out_centers[o]       = 0.9f * c0 + acc0 * inv;
    out_centers[o + 256] = 0.9f * c1 + acc1 * inv;
    out_centers[o + 512] = 0.9f * c2 + acc2 * inv;
  } else {
    out_centers[o]       = c0;
    out_centers[o + 256] = c1;
    out_centers[o + 512] = c2;
  }
}

// ---------------- Kernel D: finalize loss
__global__ __launch_bounds__(256) void finalize_kernel(const float* __restrict__ ce_p,
                                                       const float* __restrict__ sdc_p,
                                                       float* __restrict__ out) {
  __shared__ float red[256];
  int t = threadIdx.x;
  float s = 0.f;
  for (int i = t; i < 4096; i += 256) s += ce_p[i];
  float s2 = 0.f;
  for (int i = t; i < 512; i += 256) s2 += sdc_p[i];
  red[t] = s + 0.1f * s2;
  __syncthreads();
  for (int off = 128; off > 0; off >>= 1) {
    if (t < off) red[t] += red[t + off];
    __syncthreads();
  }
  if (t == 0) out[0] = red[0] * (1.0f / 16384.0f);
}

extern "C" void kernel_launch(void* const* d_in, const int* in_sizes, int n_in,
                              void* d_out, int out_size, void* d_ws, size_t ws_size,
                              hipStream_t stream) {
  const float* outputs  = (const float*)d_in[0];
  const int*   labels   = (const int*)d_in[1];
  const float* features = (const float*)d_in[2];
  const float* centers  = (const float*)d_in[3];
  float* out = (float*)d_out;

  char* ws = (char*)d_ws;
  float* p_true      = (float*)ws;                          // 16384 floats (64 KB)
  float* ce_partial  = (float*)(ws + 65536);                // 4096 floats (16 KB)
  float* sdc_partial = (float*)(ws + 65536 + 16384);        // 512 floats (2 KB)
  unsigned short* cbf = (unsigned short*)(ws + 83968);      // 1024*768 bf16 (1.5 MB)

  cvt_centers_kernel<<<(NPAD * FDIM) / 256, 256, 0, stream>>>(centers, cbf);
  ce_kernel<<<B_ROWS / 4, 256, 0, stream>>>(outputs, labels, ce_partial);
  sims_kernel<<<B_ROWS / 32, 256, 0, stream>>>(features, cbf, labels, p_true, sdc_partial);
  mstep_kernel<<<NCLS, 256, 0, stream>>>(features, centers, labels, p_true, out + 1);
  finalize_kernel<<<1, 256, 0, stream>>>(ce_partial, sdc_partial, out);
}

// Round 2
// 214.352 us; speedup vs baseline: 1.3234x; 1.3234x over previous
//
#include <hip/hip_runtime.h>
#include <hip/hip_bf16.h>
#include <cstdint>

#define B_ROWS 16384
#define NCLS 1000
#define NPAD 1024
#define FDIM 768
#define TEMP_INV 10.0f

typedef float floatx4 __attribute__((ext_vector_type(4)));
typedef short short8 __attribute__((ext_vector_type(8)));
typedef unsigned short ushort8v __attribute__((ext_vector_type(8)));

__device__ inline unsigned short f2bf(float f) {
  unsigned int u = __float_as_uint(f);
  u += 0x7FFFu + ((u >> 16) & 1u);   // round-to-nearest-even
  return (unsigned short)(u >> 16);
}

#define GLDS(gp, lp) __builtin_amdgcn_global_load_lds( \
    (const __attribute__((address_space(1))) void*)(gp), \
    (__attribute__((address_space(3))) void*)(lp), 16, 0, 0)

// ---------------- cvt: features fp32->bf16, centers fp32->bf16 zero-padded to 1024 rows
__global__ __launch_bounds__(256) void cvt_kernel(const float* __restrict__ features,
                                                  const float* __restrict__ centers,
                                                  unsigned short* __restrict__ fbf,
                                                  unsigned short* __restrict__ cbf) {
  const int NF8 = B_ROWS * FDIM / 8;   // 1,572,864
  int i = blockIdx.x * 256 + threadIdx.x;   // grid covers NF8 + NPAD*FDIM/8
  float4 v0, v1;
  unsigned short* dst;
  if (i < NF8) {
    const float4* s = reinterpret_cast<const float4*>(features) + (size_t)i * 2;
    v0 = s[0]; v1 = s[1];
    dst = fbf + (size_t)i * 8;
  } else {
    int j = i - NF8;
    if (j * 8 < NCLS * FDIM) {
      const float4* s = reinterpret_cast<const float4*>(centers) + (size_t)j * 2;
      v0 = s[0]; v1 = s[1];
    } else {
      v0.x = v0.y = v0.z = v0.w = 0.f;
      v1 = v0;
    }
    dst = cbf + (size_t)j * 8;
  }
  ushort8v o;
  o[0] = f2bf(v0.x); o[1] = f2bf(v0.y); o[2] = f2bf(v0.z); o[3] = f2bf(v0.w);
  o[4] = f2bf(v1.x); o[5] = f2bf(v1.y); o[6] = f2bf(v1.z); o[7] = f2bf(v1.w);
  *reinterpret_cast<ushort8v*>(dst) = o;
}

// ---------------- CE partials. One wave per row, 4 rows/block.
__global__ __launch_bounds__(256) void ce_kernel(const float* __restrict__ outputs,
                                                 const int* __restrict__ labels,
                                                 float* __restrict__ ce_partial) {
  __shared__ float ared[4];
  const int wid = threadIdx.x >> 6;
  const int lane = threadIdx.x & 63;
  const int b = blockIdx.x * 4 + wid;
  const float* row = outputs + (size_t)b * NCLS;
  const float4* r4 = reinterpret_cast<const float4*>(row);
  float4 v[4];
  float m = -1e30f;
#pragma unroll
  for (int it = 0; it < 4; ++it) {
    int idx = lane + it * 64;
    if (idx < 250) v[it] = r4[idx];
    else { v[it].x = -1e30f; v[it].y = -1e30f; v[it].z = -1e30f; v[it].w = -1e30f; }
    m = fmaxf(m, fmaxf(fmaxf(v[it].x, v[it].y), fmaxf(v[it].z, v[it].w)));
  }
#pragma unroll
  for (int msk = 1; msk < 64; msk <<= 1) m = fmaxf(m, __shfl_xor(m, msk));
  float s = 0.f;
#pragma unroll
  for (int it = 0; it < 4; ++it)
    s += __expf(v[it].x - m) + __expf(v[it].y - m) + __expf(v[it].z - m) + __expf(v[it].w - m);
#pragma unroll
  for (int msk = 1; msk < 64; msk <<= 1) s += __shfl_xor(s, msk);
  if (lane == 0) {
    float lse = m + logf(s);
    ared[wid] = lse - row[labels[b]];
  }
  __syncthreads();
  if (threadIdx.x == 0)
    ce_partial[blockIdx.x] = ared[0] + ared[1] + ared[2] + ared[3];
}

// ---------------- m97-style GEMM + per-colblock softmax partials.
// 128x128 tile, BK=32, 4 waves each 64x64 (4x4 frags of 16x16x32).
// Writes pm/ps[colblk][row] partial max/sumexp and scatters z_true.
__global__ __launch_bounds__(256, 2) void gemm_stats_kernel(
    const unsigned short* __restrict__ fbf,
    const unsigned short* __restrict__ cbf,
    const int* __restrict__ labels,
    float* __restrict__ pm, float* __restrict__ psv,
    float* __restrict__ ztrue) {
  __shared__ unsigned short As[128 * 32];
  __shared__ unsigned short Bs[128 * 32];
  __shared__ int lab[128];
  __shared__ float sm[128][2], ss[128][2];

  const int t = threadIdx.x;
  const int bid = blockIdx.x;
  // swizzle: 8 colblocks of a rowblock land on the same XCD (bid % 8 heuristic)
  const int rowblk = (bid & 7) + 8 * (bid >> 6);   // 0..127
  const int colblk = (bid >> 3) & 7;               // 0..7
  const int w = t >> 6, lane = t & 63;
  const int quad = lane >> 4, l15 = lane & 15;
  const int wr = w >> 1, wc = w & 1;

  if (t < 128) lab[t] = labels[rowblk * 128 + t];

  // staging chunks: 512 x 16B per tile; chunk c: row = c>>2, 16B-piece = c&3
  const int c0 = w * 128 + lane;
  const int c1 = c0 + 64;
  const unsigned short* agp0 = fbf + (size_t)(rowblk * 128 + (c0 >> 2)) * FDIM + (c0 & 3) * 8;
  const unsigned short* agp1 = fbf + (size_t)(rowblk * 128 + (c1 >> 2)) * FDIM + (c1 & 3) * 8;
  const unsigned short* bgp0 = cbf + (size_t)(colblk * 128 + (c0 >> 2)) * FDIM + (c0 & 3) * 8;
  const unsigned short* bgp1 = cbf + (size_t)(colblk * 128 + (c1 >> 2)) * FDIM + (c1 & 3) * 8;
  unsigned short* al0 = &As[(w * 2 + 0) * 512];
  unsigned short* al1 = &As[(w * 2 + 1) * 512];
  unsigned short* bl0 = &Bs[(w * 2 + 0) * 512];
  unsigned short* bl1 = &Bs[(w * 2 + 1) * 512];

  const int arow_off = (wr * 64 + l15) * 32 + quad * 8;
  const int brow_off = (wc * 64 + l15) * 32 + quad * 8;

  floatx4 acc[4][4];
#pragma unroll
  for (int i = 0; i < 4; ++i)
#pragma unroll
    for (int j = 0; j < 4; ++j) acc[i][j] = (floatx4){0.f, 0.f, 0.f, 0.f};

  for (int kk = 0; kk < 24; ++kk) {
    __syncthreads();                       // LDS safe to overwrite
    const int ko = kk * 32;
    GLDS(agp0 + ko, al0);
    GLDS(agp1 + ko, al1);
    GLDS(bgp0 + ko, bl0);
    GLDS(bgp1 + ko, bl1);
    __syncthreads();                       // tile resident
    short8 a[4], b[4];
#pragma unroll
    for (int i = 0; i < 4; ++i)
      a[i] = *reinterpret_cast<const short8*>(&As[arow_off + i * 512]);
#pragma unroll
    for (int j = 0; j < 4; ++j)
      b[j] = *reinterpret_cast<const short8*>(&Bs[brow_off + j * 512]);
#pragma unroll
    for (int i = 0; i < 4; ++i)
#pragma unroll
      for (int j = 0; j < 4; ++j)
        acc[i][j] = __builtin_amdgcn_mfma_f32_16x16x32_bf16(a[i], b[j], acc[i][j], 0, 0, 0);
  }

  // epilogue: z = 10*sims; per-row partial max/sumexp over this block's 128 cols
  const int gcol0 = colblk * 128 + wc * 64;
#pragma unroll
  for (int rb = 0; rb < 4; ++rb) {
#pragma unroll
    for (int r = 0; r < 4; ++r) {
      const int lrow = wr * 64 + rb * 16 + quad * 4 + r;
      float zv[4];
      float m = -1e30f;
#pragma unroll
      for (int cb = 0; cb < 4; ++cb) {
        float z = acc[rb][cb][r] * TEMP_INV;
        int gc = gcol0 + cb * 16 + l15;
        if (gc == lab[lrow]) ztrue[rowblk * 128 + lrow] = z;
        if (gc >= NCLS) z = -1e30f;
        zv[cb] = z;
        m = fmaxf(m, z);
      }
#pragma unroll
      for (int msk = 1; msk < 16; msk <<= 1) m = fmaxf(m, __shfl_xor(m, msk));
      float s = 0.f;
#pragma unroll
      for (int cb = 0; cb < 4; ++cb) s += __expf(zv[cb] - m);
#pragma unroll
      for (int msk = 1; msk < 16; msk <<= 1) s += __shfl_xor(s, msk);
      if (l15 == 0) { sm[lrow][wc] = m; ss[lrow][wc] = s; }
    }
  }
  __syncthreads();
  if (t < 128) {
    float m0 = sm[t][0], m1 = sm[t][1];
    float mn = fmaxf(m0, m1);
    float S = ss[t][0] * __expf(m0 - mn) + ss[t][1] * __expf(m1 - mn);
    int grow = rowblk * 128 + t;
    pm[colblk * B_ROWS + grow] = mn;
    psv[colblk * B_ROWS + grow] = S;
  }
}

// ---------------- combine: merge 8 colblock partials -> p_true, SDC partials
__global__ __launch_bounds__(256) void combine_kernel(
    const float* __restrict__ pm, const float* __restrict__ psv,
    const float* __restrict__ ztrue, float* __restrict__ p_true,
    float* __restrict__ sdc_partial) {
  __shared__ float wred[4];
  const int b = blockIdx.x * 256 + threadIdx.x;
  float mj[8];
  float M = -1e30f;
#pragma unroll
  for (int j = 0; j < 8; ++j) { mj[j] = pm[j * B_ROWS + b]; M = fmaxf(M, mj[j]); }
  float S = 0.f;
#pragma unroll
  for (int j = 0; j < 8; ++j) S += psv[j * B_ROWS + b] * __expf(mj[j] - M);
  float p = __expf(ztrue[b] - M) / S;
  p_true[b] = p;
  float v = -logf(p + 1e-8f);
#pragma unroll
  for (int msk = 1; msk < 64; msk <<= 1) v += __shfl_xor(v, msk);
  if ((threadIdx.x & 63) == 0) wred[threadIdx.x >> 6] = v;
  __syncthreads();
  if (threadIdx.x == 0)
    sdc_partial[blockIdx.x] = wred[0] + wred[1] + wred[2] + wred[3];
}

// ---------------- fallback path (round-1 kernels), used only if ws too small
__global__ void cvt_centers_kernel(const float* __restrict__ centers,
                                   unsigned short* __restrict__ cbf) {
  int i = blockIdx.x * 256 + threadIdx.x;
  float v = 0.0f;
  if (i < NCLS * FDIM) v = centers[i];
  cbf[i] = f2bf(v);
}

__global__ __launch_bounds__(256, 2) void sims_kernel(
    const float* __restrict__ features,
    const unsigned short* __restrict__ cbf,
    const int* __restrict__ labels,
    float* __restrict__ p_true,
    float* __restrict__ sdc_partial) {
  __shared__ unsigned short As[32 * 776];
  __shared__ unsigned short Bs[128 * 40];
  __shared__ float stat_m[32][4];
  __shared__ float stat_s[32][4];
  __shared__ float ztrue[32];
  __shared__ int lab[32];
  __shared__ float red[32];

  const int t = threadIdx.x;
  const int rb0 = blockIdx.x * 32;
  const int w = t >> 6;
  const int lane = t & 63;
  const int quad = lane >> 4;
  const int l15 = lane & 15;

  if (t < 32) {
    lab[t] = labels[rb0 + t];
#pragma unroll
    for (int g = 0; g < 4; ++g) { stat_m[t][g] = -1e30f; stat_s[t][g] = 0.f; }
  }
  {
    const float4* f4 = reinterpret_cast<const float4*>(features + (size_t)rb0 * FDIM);
    for (int it = 0; it < 24; ++it) {
      int i = t + 256 * it;
      int row = i / 192;
      int c4 = i - row * 192;
      float4 v = f4[i];
      ushort4 o;
      o.x = f2bf(v.x); o.y = f2bf(v.y); o.z = f2bf(v.z); o.w = f2bf(v.w);
      *reinterpret_cast<ushort4*>(&As[row * 776 + c4 * 4]) = o;
    }
  }
  __syncthreads();

  for (int ct = 0; ct < 8; ++ct) {
    floatx4 acc00 = {0.f, 0.f, 0.f, 0.f};
    floatx4 acc01 = acc00, acc10 = acc00, acc11 = acc00;
    for (int ks = 0; ks < 24; ++ks) {
#pragma unroll
      for (int rr = 0; rr < 2; ++rr) {
        int cidx = t + 256 * rr;
        int brow = cidx >> 2, ch = cidx & 3;
        ushort8v v = *reinterpret_cast<const ushort8v*>(
            cbf + (size_t)(ct * 128 + brow) * FDIM + ks * 32 + ch * 8);
        *reinterpret_cast<ushort8v*>(&Bs[brow * 40 + ch * 8]) = v;
      }
      __syncthreads();
      short8 a0 = *reinterpret_cast<const short8*>(&As[l15 * 776 + ks * 32 + quad * 8]);
      short8 a1 = *reinterpret_cast<const short8*>(&As[(16 + l15) * 776 + ks * 32 + quad * 8]);
      short8 b0 = *reinterpret_cast<const short8*>(&Bs[(w * 32 + l15) * 40 + quad * 8]);
      short8 b1 = *reinterpret_cast<const short8*>(&Bs[(w * 32 + 16 + l15) * 40 + quad * 8]);
      acc00 = __builtin_amdgcn_mfma_f32_16x16x32_bf16(a0, b0, acc00, 0, 0, 0);
      acc01 = __builtin_amdgcn_mfma_f32_16x16x32_bf16(a0, b1, acc01, 0, 0, 0);
      acc10 = __builtin_amdgcn_mfma_f32_16x16x32_bf16(a1, b0, acc10, 0, 0, 0);
      acc11 = __builtin_amdgcn_mfma_f32_16x16x32_bf16(a1, b1, acc11, 0, 0, 0);
      __syncthreads();
    }
    int cb = ct * 128 + w * 32;
#pragma unroll
    for (int fr = 0; fr < 2; ++fr) {
#pragma unroll
      for (int r = 0; r < 4; ++r) {
        float z0 = (fr == 0 ? acc00[r] : acc10[r]) * TEMP_INV;
        float z1 = (fr == 0 ? acc01[r] : acc11[r]) * TEMP_INV;
        int rowl = fr * 16 + quad * 4 + r;
        int c0 = cb + l15;
        int c1 = cb + 16 + l15;
        int lb = lab[rowl];
        if (c0 == lb) ztrue[rowl] = z0;
        if (c1 == lb) ztrue[rowl] = z1;
        if (c0 >= NCLS) z0 = -1e30f;
        if (c1 >= NCLS) z1 = -1e30f;
        float m = fmaxf(z0, z1);
#pragma unroll
        for (int msk = 1; msk < 16; msk <<= 1) m = fmaxf(m, __shfl_xor(m, msk));
        float s = __expf(z0 - m) + __expf(z1 - m);
#pragma unroll
        for (int msk = 1; msk < 16; msk <<= 1) s += __shfl_xor(s, msk);
        if (l15 == 0) {
          float mo = stat_m[rowl][w], so = stat_s[rowl][w];
          float mn = fmaxf(mo, m);
          stat_s[rowl][w] = so * __expf(mo - mn) + s * __expf(m - mn);
          stat_m[rowl][w] = mn;
        }
      }
    }
  }
  __syncthreads();
  if (t < 32) {
    float mn = fmaxf(fmaxf(stat_m[t][0], stat_m[t][1]), fmaxf(stat_m[t][2], stat_m[t][3]));
    float S = stat_s[t][0] * __expf(stat_m[t][0] - mn)
            + stat_s[t][1] * __expf(stat_m[t][1] - mn)
            + stat_s[t][2] * __expf(stat_m[t][2] - mn)
            + stat_s[t][3] * __expf(stat_m[t][3] - mn);
    float p = __expf(ztrue[t] - mn) / S;
    p_true[rb0 + t] = p;
    red[t] = -logf(p + 1e-8f);
  }
  __syncthreads();
  if (t == 0) {
    float s = 0.f;
#pragma unroll
    for (int i = 0; i < 32; ++i) s += red[i];
    sdc_partial[blockIdx.x] = s;
  }
}

// ---------------- M-step, one block per class.
__global__ __launch_bounds__(256) void mstep_kernel(
    const float* __restrict__ features,
    const float* __restrict__ centers,
    const int* __restrict__ labels,
    const float* __restrict__ p_true,
    float* __restrict__ out_centers) {
  __shared__ int idxs[2048];
  __shared__ float ps[2048];
  __shared__ int cnt;
  const int c = blockIdx.x;
  const int t = threadIdx.x;
  float acc0 = 0.f, acc1 = 0.f, acc2 = 0.f, wsum = 0.f;
  for (int chunk = 0; chunk < B_ROWS; chunk += 2048) {
    if (t == 0) cnt = 0;
    __syncthreads();
    for (int j = t; j < 2048; j += 256) {
      int b = chunk + j;
      if (labels[b] == c) {
        int k = atomicAdd(&cnt, 1);
        idxs[k] = b;
        ps[k] = p_true[b];
      }
    }
    __syncthreads();
    int n = cnt;
    for (int j = 0; j < n; ++j) {
      int b = idxs[j];
      float p = ps[j];
      const float* f = features + (size_t)b * FDIM;
      acc0 += p * f[t];
      acc1 += p * f[t + 256];
      acc2 += p * f[t + 512];
      wsum += p;
    }
    __syncthreads();
  }
  const float* crow = centers + (size_t)c * FDIM;
  float c0 = crow[t], c1 = crow[t + 256], c2 = crow[t + 512];
  size_t o = (size_t)c * FDIM + t;
  if (wsum > 0.f) {
    float inv = 0.1f / (wsum + 1e-8f);
    out_centers[o]       = 0.9f * c0 + acc0 * inv;
    out_centers[o + 256] = 0.9f * c1 + acc1 * inv;
    out_centers[o + 512] = 0.9f * c2 + acc2 * inv;
  } else {
    out_centers[o]       = c0;
    out_centers[o + 256] = c1;
    out_centers[o + 512] = c2;
  }
}

// ---------------- finalize loss
__global__ __launch_bounds__(256) void finalize_kernel(const float* __restrict__ ce_p,
                                                       const float* __restrict__ sdc_p,
                                                       float* __restrict__ out,
                                                       int n_sdc) {
  __shared__ float red[256];
  int t = threadIdx.x;
  float s = 0.f;
  for (int i = t; i < 4096; i += 256) s += ce_p[i];
  float s2 = 0.f;
  for (int i = t; i < n_sdc; i += 256) s2 += sdc_p[i];
  red[t] = s + 0.1f * s2;
  __syncthreads();
  for (int off = 128; off > 0; off >>= 1) {
    if (t < off) red[t] += red[t + off];
    __syncthreads();
  }
  if (t == 0) out[0] = red[0] * (1.0f / 16384.0f);
}

extern "C" void kernel_launch(void* const* d_in, const int* in_sizes, int n_in,
                              void* d_out, int out_size, void* d_ws, size_t ws_size,
                              hipStream_t stream) {
  const float* outputs  = (const float*)d_in[0];
  const int*   labels   = (const int*)d_in[1];
  const float* features = (const float*)d_in[2];
  const float* centers  = (const float*)d_in[3];
  float* out = (float*)d_out;

  char* ws = (char*)d_ws;
  float* p_true      = (float*)(ws);                        // 64 KB
  float* ztrue       = (float*)(ws + (64 << 10));           // 64 KB
  float* ce_partial  = (float*)(ws + (128 << 10));          // 16 KB
  float* sdc_partial = (float*)(ws + (144 << 10));          // 2 KB (<=512 floats)
  float* pm          = (float*)(ws + (148 << 10));          // 512 KB
  float* psv         = (float*)(ws + (660 << 10));          // 512 KB
  unsigned short* cbf = (unsigned short*)(ws + (1172 << 10)); // 1.5 MB
  unsigned short* fbf = (unsigned short*)(ws + (2708 << 10)); // 24 MB
  const size_t need = (2708ull << 10) + 2ull * B_ROWS * FDIM;

  ce_kernel<<<B_ROWS / 4, 256, 0, stream>>>(outputs, labels, ce_partial);

  int n_sdc;
  if (ws_size >= need) {
    const int NTOT8 = (B_ROWS * FDIM + NPAD * FDIM) / 8;    // 1,671,168
    cvt_kernel<<<NTOT8 / 256, 256, 0, stream>>>(features, centers, fbf, cbf);
    gemm_stats_kernel<<<1024, 256, 0, stream>>>(fbf, cbf, labels, pm, psv, ztrue);
    combine_kernel<<<B_ROWS / 256, 256, 0, stream>>>(pm, psv, ztrue, p_true, sdc_partial);
    n_sdc = B_ROWS / 256;
  } else {
    cvt_centers_kernel<<<(NPAD * FDIM) / 256, 256, 0, stream>>>(centers, cbf);
    sims_kernel<<<B_ROWS / 32, 256, 0, stream>>>(features, cbf, labels, p_true, sdc_partial);
    n_sdc = B_ROWS / 32;
  }
  mstep_kernel<<<NCLS, 256, 0, stream>>>(features, centers, labels, p_true, out + 1);
  finalize_kernel<<<1, 256, 0, stream>>>(ce_partial, sdc_partial, out, n_sdc);
}

// Round 3
// 194.307 us; speedup vs baseline: 1.4599x; 1.1032x over previous
//
#include <hip/hip_runtime.h>
#include <hip/hip_bf16.h>
#include <cstdint>

#define B_ROWS 16384
#define NCLS 1000
#define NPAD 1024
#define FDIM 768
#define TEMP_INV 10.0f
#define BCAP 128

typedef float floatx4 __attribute__((ext_vector_type(4)));
typedef short short8 __attribute__((ext_vector_type(8)));
typedef unsigned short ushort8v __attribute__((ext_vector_type(8)));

__device__ inline unsigned short f2bf(float f) {
  unsigned int u = __float_as_uint(f);
  u += 0x7FFFu + ((u >> 16) & 1u);   // round-to-nearest-even
  return (unsigned short)(u >> 16);
}

#define GLDS(gp, lp) __builtin_amdgcn_global_load_lds( \
    (const __attribute__((address_space(1))) void*)(gp), \
    (__attribute__((address_space(3))) void*)(lp), 16, 0, 0)

#define CVT_BLOCKS 6528   // (16384*768 + 1024*768)/8/256
#define CE_BLOCKS  4096   // 16384/4

// ---------------- prep: fused [cvt features+centers -> bf16] + [CE partials]
__global__ __launch_bounds__(256) void prep_kernel(
    const float* __restrict__ outputs, const int* __restrict__ labels,
    const float* __restrict__ features, const float* __restrict__ centers,
    unsigned short* __restrict__ fbf, unsigned short* __restrict__ cbf,
    float* __restrict__ ce_partial) {
  const int bid = blockIdx.x;
  if (bid < CVT_BLOCKS) {
    const int NF8 = B_ROWS * FDIM / 8;
    int i = bid * 256 + threadIdx.x;
    float4 v0, v1;
    unsigned short* dst;
    if (i < NF8) {
      const float4* s = reinterpret_cast<const float4*>(features) + (size_t)i * 2;
      v0 = s[0]; v1 = s[1];
      dst = fbf + (size_t)i * 8;
    } else {
      int j = i - NF8;
      if (j * 8 < NCLS * FDIM) {
        const float4* s = reinterpret_cast<const float4*>(centers) + (size_t)j * 2;
        v0 = s[0]; v1 = s[1];
      } else {
        v0.x = v0.y = v0.z = v0.w = 0.f;
        v1 = v0;
      }
      dst = cbf + (size_t)j * 8;
    }
    ushort8v o;
    o[0] = f2bf(v0.x); o[1] = f2bf(v0.y); o[2] = f2bf(v0.z); o[3] = f2bf(v0.w);
    o[4] = f2bf(v1.x); o[5] = f2bf(v1.y); o[6] = f2bf(v1.z); o[7] = f2bf(v1.w);
    *reinterpret_cast<ushort8v*>(dst) = o;
  } else {
    // CE: one wave per row, 4 rows/block
    __shared__ float ared[4];
    const int cb = bid - CVT_BLOCKS;
    const int wid = threadIdx.x >> 6;
    const int lane = threadIdx.x & 63;
    const int b = cb * 4 + wid;
    const float* row = outputs + (size_t)b * NCLS;
    const float4* r4 = reinterpret_cast<const float4*>(row);
    float4 v[4];
    float m = -1e30f;
#pragma unroll
    for (int it = 0; it < 4; ++it) {
      int idx = lane + it * 64;
      if (idx < 250) v[it] = r4[idx];
      else { v[it].x = -1e30f; v[it].y = -1e30f; v[it].z = -1e30f; v[it].w = -1e30f; }
      m = fmaxf(m, fmaxf(fmaxf(v[it].x, v[it].y), fmaxf(v[it].z, v[it].w)));
    }
#pragma unroll
    for (int msk = 1; msk < 64; msk <<= 1) m = fmaxf(m, __shfl_xor(m, msk));
    float s = 0.f;
#pragma unroll
    for (int it = 0; it < 4; ++it)
      s += __expf(v[it].x - m) + __expf(v[it].y - m) + __expf(v[it].z - m) + __expf(v[it].w - m);
#pragma unroll
    for (int msk = 1; msk < 64; msk <<= 1) s += __shfl_xor(s, msk);
    if (lane == 0) {
      float lse = m + logf(s);
      ared[wid] = lse - row[labels[b]];
    }
    __syncthreads();
    if (threadIdx.x == 0)
      ce_partial[cb] = ared[0] + ared[1] + ared[2] + ared[3];
  }
}

// ---------------- m97-style GEMM + per-colblock softmax partials.
__global__ __launch_bounds__(256, 2) void gemm_stats_kernel(
    const unsigned short* __restrict__ fbf,
    const unsigned short* __restrict__ cbf,
    const int* __restrict__ labels,
    float* __restrict__ pm, float* __restrict__ psv,
    float* __restrict__ ztrue, int* __restrict__ bcnt) {
  __shared__ unsigned short As[128 * 32];
  __shared__ unsigned short Bs[128 * 32];
  __shared__ int lab[128];
  __shared__ float sm[128][2], ss[128][2];

  const int t = threadIdx.x;
  const int bid = blockIdx.x;
  if (t == 0 && bid < NCLS) bcnt[bid] = 0;   // zero bucket counters for combine

  const int rowblk = (bid & 7) + 8 * (bid >> 6);   // 8 colblocks/rowblock share an XCD
  const int colblk = (bid >> 3) & 7;
  const int w = t >> 6, lane = t & 63;
  const int quad = lane >> 4, l15 = lane & 15;
  const int wr = w >> 1, wc = w & 1;

  if (t < 128) lab[t] = labels[rowblk * 128 + t];

  const int c0 = w * 128 + lane;
  const int c1 = c0 + 64;
  const unsigned short* agp0 = fbf + (size_t)(rowblk * 128 + (c0 >> 2)) * FDIM + (c0 & 3) * 8;
  const unsigned short* agp1 = fbf + (size_t)(rowblk * 128 + (c1 >> 2)) * FDIM + (c1 & 3) * 8;
  const unsigned short* bgp0 = cbf + (size_t)(colblk * 128 + (c0 >> 2)) * FDIM + (c0 & 3) * 8;
  const unsigned short* bgp1 = cbf + (size_t)(colblk * 128 + (c1 >> 2)) * FDIM + (c1 & 3) * 8;
  unsigned short* al0 = &As[(w * 2 + 0) * 512];
  unsigned short* al1 = &As[(w * 2 + 1) * 512];
  unsigned short* bl0 = &Bs[(w * 2 + 0) * 512];
  unsigned short* bl1 = &Bs[(w * 2 + 1) * 512];

  const int arow_off = (wr * 64 + l15) * 32 + quad * 8;
  const int brow_off = (wc * 64 + l15) * 32 + quad * 8;

  floatx4 acc[4][4];
#pragma unroll
  for (int i = 0; i < 4; ++i)
#pragma unroll
    for (int j = 0; j < 4; ++j) acc[i][j] = (floatx4){0.f, 0.f, 0.f, 0.f};

  for (int kk = 0; kk < 24; ++kk) {
    __syncthreads();
    const int ko = kk * 32;
    GLDS(agp0 + ko, al0);
    GLDS(agp1 + ko, al1);
    GLDS(bgp0 + ko, bl0);
    GLDS(bgp1 + ko, bl1);
    __syncthreads();
    short8 a[4], b[4];
#pragma unroll
    for (int i = 0; i < 4; ++i)
      a[i] = *reinterpret_cast<const short8*>(&As[arow_off + i * 512]);
#pragma unroll
    for (int j = 0; j < 4; ++j)
      b[j] = *reinterpret_cast<const short8*>(&Bs[brow_off + j * 512]);
#pragma unroll
    for (int i = 0; i < 4; ++i)
#pragma unroll
      for (int j = 0; j < 4; ++j)
        acc[i][j] = __builtin_amdgcn_mfma_f32_16x16x32_bf16(a[i], b[j], acc[i][j], 0, 0, 0);
  }

  const int gcol0 = colblk * 128 + wc * 64;
#pragma unroll
  for (int rb = 0; rb < 4; ++rb) {
#pragma unroll
    for (int r = 0; r < 4; ++r) {
      const int lrow = wr * 64 + rb * 16 + quad * 4 + r;
      float zv[4];
      float m = -1e30f;
#pragma unroll
      for (int cb = 0; cb < 4; ++cb) {
        float z = acc[rb][cb][r] * TEMP_INV;
        int gc = gcol0 + cb * 16 + l15;
        if (gc == lab[lrow]) ztrue[rowblk * 128 + lrow] = z;
        if (gc >= NCLS) z = -1e30f;
        zv[cb] = z;
        m = fmaxf(m, z);
      }
#pragma unroll
      for (int msk = 1; msk < 16; msk <<= 1) m = fmaxf(m, __shfl_xor(m, msk));
      float s = 0.f;
#pragma unroll
      for (int cb = 0; cb < 4; ++cb) s += __expf(zv[cb] - m);
#pragma unroll
      for (int msk = 1; msk < 16; msk <<= 1) s += __shfl_xor(s, msk);
      if (l15 == 0) { sm[lrow][wc] = m; ss[lrow][wc] = s; }
    }
  }
  __syncthreads();
  if (t < 128) {
    float m0 = sm[t][0], m1 = sm[t][1];
    float mn = fmaxf(m0, m1);
    float S = ss[t][0] * __expf(m0 - mn) + ss[t][1] * __expf(m1 - mn);
    int grow = rowblk * 128 + t;
    pm[colblk * B_ROWS + grow] = mn;
    psv[colblk * B_ROWS + grow] = S;
  }
}

// ---------------- combine: merge partials -> p, SDC partials, class buckets
__global__ __launch_bounds__(256) void combine_kernel(
    const float* __restrict__ pm, const float* __restrict__ psv,
    const float* __restrict__ ztrue, const int* __restrict__ labels,
    int* __restrict__ bcnt, int* __restrict__ bidx, float* __restrict__ bp,
    float* __restrict__ sdc_partial) {
  __shared__ float wred[4];
  const int b = blockIdx.x * 256 + threadIdx.x;
  float mj[8];
  float M = -1e30f;
#pragma unroll
  for (int j = 0; j < 8; ++j) { mj[j] = pm[j * B_ROWS + b]; M = fmaxf(M, mj[j]); }
  float S = 0.f;
#pragma unroll
  for (int j = 0; j < 8; ++j) S += psv[j * B_ROWS + b] * __expf(mj[j] - M);
  float p = __expf(ztrue[b] - M) / S;
  int lb = labels[b];
  int slot = atomicAdd(&bcnt[lb], 1);
  if (slot < BCAP) { bidx[lb * BCAP + slot] = b; bp[lb * BCAP + slot] = p; }
  float v = -logf(p + 1e-8f);
#pragma unroll
  for (int msk = 1; msk < 64; msk <<= 1) v += __shfl_xor(v, msk);
  if ((threadIdx.x & 63) == 0) wred[threadIdx.x >> 6] = v;
  __syncthreads();
  if (threadIdx.x == 0)
    sdc_partial[blockIdx.x] = wred[0] + wred[1] + wred[2] + wred[3];
}

// ---------------- mstep: one block per class, direct bucket gather.
// Block 0 additionally finalizes the scalar loss.
__global__ __launch_bounds__(256) void mstep_kernel(
    const float* __restrict__ features,
    const float* __restrict__ centers,
    const int* __restrict__ bcnt, const int* __restrict__ bidx,
    const float* __restrict__ bp,
    const float* __restrict__ ce_partial, const float* __restrict__ sdc_partial,
    float* __restrict__ out_loss, float* __restrict__ out_centers) {
  const int c = blockIdx.x;
  const int t = threadIdx.x;
  if (c == 0) {
    __shared__ float red[256];
    float s = 0.f;
    for (int i = t; i < CE_BLOCKS; i += 256) s += ce_partial[i];
    float s2 = 0.f;
    for (int i = t; i < 64; i += 256) s2 += sdc_partial[i];
    red[t] = s + 0.1f * s2;
    __syncthreads();
    for (int off = 128; off > 0; off >>= 1) {
      if (t < off) red[t] += red[t + off];
      __syncthreads();
    }
    if (t == 0) out_loss[0] = red[0] * (1.0f / 16384.0f);
  }
  int n = bcnt[c];
  if (n > BCAP) n = BCAP;
  float a0 = 0.f, a1 = 0.f, a2 = 0.f, ws = 0.f;
  int j = 0;
  for (; j + 2 <= n; j += 2) {
    int b0 = bidx[c * BCAP + j], b1 = bidx[c * BCAP + j + 1];
    float p0 = bp[c * BCAP + j], p1 = bp[c * BCAP + j + 1];
    const float* f0 = features + (size_t)b0 * FDIM;
    const float* f1 = features + (size_t)b1 * FDIM;
    float x00 = f0[t], x01 = f0[t + 256], x02 = f0[t + 512];
    float x10 = f1[t], x11 = f1[t + 256], x12 = f1[t + 512];
    a0 += p0 * x00 + p1 * x10;
    a1 += p0 * x01 + p1 * x11;
    a2 += p0 * x02 + p1 * x12;
    ws += p0 + p1;
  }
  if (j < n) {
    int b0 = bidx[c * BCAP + j];
    float p0 = bp[c * BCAP + j];
    const float* f0 = features + (size_t)b0 * FDIM;
    a0 += p0 * f0[t]; a1 += p0 * f0[t + 256]; a2 += p0 * f0[t + 512];
    ws += p0;
  }
  const float* crow = centers + (size_t)c * FDIM;
  float c0 = crow[t], c1 = crow[t + 256], c2 = crow[t + 512];
  size_t o = (size_t)c * FDIM + t;
  if (ws > 0.f) {
    float inv = 0.1f / (ws + 1e-8f);
    out_centers[o]       = 0.9f * c0 + a0 * inv;
    out_centers[o + 256] = 0.9f * c1 + a1 * inv;
    out_centers[o + 512] = 0.9f * c2 + a2 * inv;
  } else {
    out_centers[o]       = c0;
    out_centers[o + 256] = c1;
    out_centers[o + 512] = c2;
  }
}

extern "C" void kernel_launch(void* const* d_in, const int* in_sizes, int n_in,
                              void* d_out, int out_size, void* d_ws, size_t ws_size,
                              hipStream_t stream) {
  const float* outputs  = (const float*)d_in[0];
  const int*   labels   = (const int*)d_in[1];
  const float* features = (const float*)d_in[2];
  const float* centers  = (const float*)d_in[3];
  float* out = (float*)d_out;

  char* ws = (char*)d_ws;
  float* ztrue       = (float*)(ws);                          // 64 KB
  float* ce_partial  = (float*)(ws + (64 << 10));             // 16 KB
  float* sdc_partial = (float*)(ws + (80 << 10));             // 1 KB
  int*   bcnt        = (int*)(ws + (84 << 10));               // 4 KB
  float* pm          = (float*)(ws + (88 << 10));             // 512 KB
  float* psv         = (float*)(ws + (600 << 10));            // 512 KB
  unsigned short* cbf = (unsigned short*)(ws + (1112 << 10)); // 1.5 MB
  unsigned short* fbf = (unsigned short*)(ws + (2648 << 10)); // 24 MB
  // buckets overlay fbf (dead after gemm; written in combine, read in mstep)
  int*   bidx        = (int*)(ws + (2648 << 10));             // 512 KB
  float* bp          = (float*)(ws + (3160 << 10));           // 512 KB

  prep_kernel<<<CVT_BLOCKS + CE_BLOCKS, 256, 0, stream>>>(
      outputs, labels, features, centers, fbf, cbf, ce_partial);
  gemm_stats_kernel<<<1024, 256, 0, stream>>>(fbf, cbf, labels, pm, psv, ztrue, bcnt);
  combine_kernel<<<B_ROWS / 256, 256, 0, stream>>>(pm, psv, ztrue, labels,
                                                   bcnt, bidx, bp, sdc_partial);
  mstep_kernel<<<NCLS, 256, 0, stream>>>(features, centers, bcnt, bidx, bp,
                                         ce_partial, sdc_partial, out, out + 1);
}

// Round 4
// 193.600 us; speedup vs baseline: 1.4652x; 1.0037x over previous
//
#include <hip/hip_runtime.h>
#include <hip/hip_bf16.h>
#include <cstdint>

#define B_ROWS 16384
#define NCLS 1000
#define NPAD 1024
#define FDIM 768
#define TEMP_INV 10.0f
#define BCAP 128

typedef float floatx4 __attribute__((ext_vector_type(4)));
typedef short short8 __attribute__((ext_vector_type(8)));
typedef unsigned short ushort8v __attribute__((ext_vector_type(8)));

__device__ inline unsigned short f2bf(float f) {
  unsigned int u = __float_as_uint(f);
  u += 0x7FFFu + ((u >> 16) & 1u);   // round-to-nearest-even
  return (unsigned short)(u >> 16);
}

#define GLDS(gp, lp) __builtin_amdgcn_global_load_lds( \
    (const __attribute__((address_space(1))) void*)(gp), \
    (__attribute__((address_space(3))) void*)(lp), 16, 0, 0)

#define CVT_BLOCKS 6528   // (16384*768 + 1024*768)/8/256
#define CE_BLOCKS  4096   // 16384/4

// ---------------- prep: fused [cvt features+centers -> bf16] + [CE partials]
__global__ __launch_bounds__(256) void prep_kernel(
    const float* __restrict__ outputs, const int* __restrict__ labels,
    const float* __restrict__ features, const float* __restrict__ centers,
    unsigned short* __restrict__ fbf, unsigned short* __restrict__ cbf,
    float* __restrict__ ce_partial) {
  const int bid = blockIdx.x;
  if (bid < CVT_BLOCKS) {
    const int NF8 = B_ROWS * FDIM / 8;
    int i = bid * 256 + threadIdx.x;
    float4 v0, v1;
    unsigned short* dst;
    if (i < NF8) {
      const float4* s = reinterpret_cast<const float4*>(features) + (size_t)i * 2;
      v0 = s[0]; v1 = s[1];
      dst = fbf + (size_t)i * 8;
    } else {
      int j = i - NF8;
      if (j * 8 < NCLS * FDIM) {
        const float4* s = reinterpret_cast<const float4*>(centers) + (size_t)j * 2;
        v0 = s[0]; v1 = s[1];
      } else {
        v0.x = v0.y = v0.z = v0.w = 0.f;
        v1 = v0;
      }
      dst = cbf + (size_t)j * 8;
    }
    ushort8v o;
    o[0] = f2bf(v0.x); o[1] = f2bf(v0.y); o[2] = f2bf(v0.z); o[3] = f2bf(v0.w);
    o[4] = f2bf(v1.x); o[5] = f2bf(v1.y); o[6] = f2bf(v1.z); o[7] = f2bf(v1.w);
    *reinterpret_cast<ushort8v*>(dst) = o;
  } else {
    // CE: one wave per row, 4 rows/block
    __shared__ float ared[4];
    const int cb = bid - CVT_BLOCKS;
    const int wid = threadIdx.x >> 6;
    const int lane = threadIdx.x & 63;
    const int b = cb * 4 + wid;
    const float* row = outputs + (size_t)b * NCLS;
    const float4* r4 = reinterpret_cast<const float4*>(row);
    float4 v[4];
    float m = -1e30f;
#pragma unroll
    for (int it = 0; it < 4; ++it) {
      int idx = lane + it * 64;
      if (idx < 250) v[it] = r4[idx];
      else { v[it].x = -1e30f; v[it].y = -1e30f; v[it].z = -1e30f; v[it].w = -1e30f; }
      m = fmaxf(m, fmaxf(fmaxf(v[it].x, v[it].y), fmaxf(v[it].z, v[it].w)));
    }
#pragma unroll
    for (int msk = 1; msk < 64; msk <<= 1) m = fmaxf(m, __shfl_xor(m, msk));
    float s = 0.f;
#pragma unroll
    for (int it = 0; it < 4; ++it)
      s += __expf(v[it].x - m) + __expf(v[it].y - m) + __expf(v[it].z - m) + __expf(v[it].w - m);
#pragma unroll
    for (int msk = 1; msk < 64; msk <<= 1) s += __shfl_xor(s, msk);
    if (lane == 0) {
      float lse = m + logf(s);
      ared[wid] = lse - row[labels[b]];
    }
    __syncthreads();
    if (threadIdx.x == 0)
      ce_partial[cb] = ared[0] + ared[1] + ared[2] + ared[3];
  }
}

// ---------------- GEMM + per-colblock softmax partials.
// Tile 64x128, BK=64, 12 k-iters. 4 waves, wave tile 32x64.
// XOR-swizzled LDS (piece ^ row&7): GLDS-compatible (scatter on global side,
// LDS contiguous), coalesced global fetch, conflict-free ds_read_b128.
__global__ __launch_bounds__(256) void gemm_stats_kernel(
    const unsigned short* __restrict__ fbf,
    const unsigned short* __restrict__ cbf,
    const int* __restrict__ labels,
    float* __restrict__ pm, float* __restrict__ psv,
    float* __restrict__ ztrue, int* __restrict__ bcnt) {
  __shared__ __align__(16) unsigned short As[64 * 64];    // 8 KB
  __shared__ __align__(16) unsigned short Bs[128 * 64];   // 16 KB
  __shared__ int lab[64];
  __shared__ float sm[64][2], ss[64][2];

  const int t = threadIdx.x;
  const int bid = blockIdx.x;
  if (t == 0 && bid < NCLS) bcnt[bid] = 0;   // zero bucket counters for combine

  const int rowblk = (bid & 7) + 8 * (bid >> 6);   // 0..255; 8 colblks share an XCD
  const int colblk = (bid >> 3) & 7;               // 0..7
  const int w = t >> 6, lane = t & 63;
  const int quad = lane >> 4, l15 = lane & 15;
  const int wr = w >> 1, wc = w & 1;

  if (t < 64) lab[t] = labels[rowblk * 64 + t];

  // staging: chunk p (16B) -> LDS offset p*16; global piece = (p&7)^(row&7)
  const int tq = t >> 3, tr = t & 7;
  const int gp = tr ^ (tq & 7);
  const unsigned short* agp0 = fbf + (size_t)(rowblk * 64 + 0 * 32 + tq) * FDIM + gp * 8;
  const unsigned short* agp1 = fbf + (size_t)(rowblk * 64 + 1 * 32 + tq) * FDIM + gp * 8;
  const unsigned short* bgp0 = cbf + (size_t)(colblk * 128 + 0 * 32 + tq) * FDIM + gp * 8;
  const unsigned short* bgp1 = cbf + (size_t)(colblk * 128 + 1 * 32 + tq) * FDIM + gp * 8;
  const unsigned short* bgp2 = cbf + (size_t)(colblk * 128 + 2 * 32 + tq) * FDIM + gp * 8;
  const unsigned short* bgp3 = cbf + (size_t)(colblk * 128 + 3 * 32 + tq) * FDIM + gp * 8;
  unsigned short* al0 = &As[(0 * 256 + w * 64) * 8];
  unsigned short* al1 = &As[(1 * 256 + w * 64) * 8];
  unsigned short* bl0 = &Bs[(0 * 256 + w * 64) * 8];
  unsigned short* bl1 = &Bs[(1 * 256 + w * 64) * 8];
  unsigned short* bl2 = &Bs[(2 * 256 + w * 64) * 8];
  unsigned short* bl3 = &Bs[(3 * 256 + w * 64) * 8];

  const int swz = l15 & 7;

  floatx4 acc[2][4];
#pragma unroll
  for (int i = 0; i < 2; ++i)
#pragma unroll
    for (int j = 0; j < 4; ++j) acc[i][j] = (floatx4){0.f, 0.f, 0.f, 0.f};

#pragma unroll
  for (int kk = 0; kk < 12; ++kk) {
    __syncthreads();                       // prev tile fully consumed
    const int ko = kk * 64;
    GLDS(agp0 + ko, al0);
    GLDS(agp1 + ko, al1);
    GLDS(bgp0 + ko, bl0);
    GLDS(bgp1 + ko, bl1);
    GLDS(bgp2 + ko, bl2);
    GLDS(bgp3 + ko, bl3);
    __syncthreads();                       // tile resident
    short8 a[2][2], b[4][2];
#pragma unroll
    for (int ks = 0; ks < 2; ++ks) {
      const int qs = ((ks * 4 + quad) ^ swz) * 8;
#pragma unroll
      for (int rb = 0; rb < 2; ++rb)
        a[rb][ks] = *reinterpret_cast<const short8*>(&As[(wr * 32 + rb * 16 + l15) * 64 + qs]);
#pragma unroll
      for (int cb = 0; cb < 4; ++cb)
        b[cb][ks] = *reinterpret_cast<const short8*>(&Bs[(wc * 64 + cb * 16 + l15) * 64 + qs]);
    }
#pragma unroll
    for (int ks = 0; ks < 2; ++ks)
#pragma unroll
      for (int rb = 0; rb < 2; ++rb)
#pragma unroll
        for (int cb = 0; cb < 4; ++cb)
          acc[rb][cb] = __builtin_amdgcn_mfma_f32_16x16x32_bf16(a[rb][ks], b[cb][ks], acc[rb][cb], 0, 0, 0);
  }

  // epilogue: z = 10*sims; per-row partial max/sumexp over this block's 128 cols
  const int gcol0 = colblk * 128 + wc * 64;
#pragma unroll
  for (int rb = 0; rb < 2; ++rb) {
#pragma unroll
    for (int r = 0; r < 4; ++r) {
      const int lrow = wr * 32 + rb * 16 + quad * 4 + r;
      float zv[4];
      float m = -1e30f;
#pragma unroll
      for (int cb = 0; cb < 4; ++cb) {
        float z = acc[rb][cb][r] * TEMP_INV;
        int gc = gcol0 + cb * 16 + l15;
        if (gc == lab[lrow]) ztrue[rowblk * 64 + lrow] = z;
        if (gc >= NCLS) z = -1e30f;
        zv[cb] = z;
        m = fmaxf(m, z);
      }
#pragma unroll
      for (int msk = 1; msk < 16; msk <<= 1) m = fmaxf(m, __shfl_xor(m, msk));
      float s = 0.f;
#pragma unroll
      for (int cb = 0; cb < 4; ++cb) s += __expf(zv[cb] - m);
#pragma unroll
      for (int msk = 1; msk < 16; msk <<= 1) s += __shfl_xor(s, msk);
      if (l15 == 0) { sm[lrow][wc] = m; ss[lrow][wc] = s; }
    }
  }
  __syncthreads();
  if (t < 64) {
    float m0 = sm[t][0], m1 = sm[t][1];
    float mn = fmaxf(m0, m1);
    float S = ss[t][0] * __expf(m0 - mn) + ss[t][1] * __expf(m1 - mn);
    int grow = rowblk * 64 + t;
    pm[colblk * B_ROWS + grow] = mn;
    psv[colblk * B_ROWS + grow] = S;
  }
}

// ---------------- combine: merge partials -> p, SDC partials, class buckets
__global__ __launch_bounds__(256) void combine_kernel(
    const float* __restrict__ pm, const float* __restrict__ psv,
    const float* __restrict__ ztrue, const int* __restrict__ labels,
    int* __restrict__ bcnt, int* __restrict__ bidx, float* __restrict__ bp,
    float* __restrict__ sdc_partial) {
  __shared__ float wred[4];
  const int b = blockIdx.x * 256 + threadIdx.x;
  float mj[8];
  float M = -1e30f;
#pragma unroll
  for (int j = 0; j < 8; ++j) { mj[j] = pm[j * B_ROWS + b]; M = fmaxf(M, mj[j]); }
  float S = 0.f;
#pragma unroll
  for (int j = 0; j < 8; ++j) S += psv[j * B_ROWS + b] * __expf(mj[j] - M);
  float p = __expf(ztrue[b] - M) / S;
  int lb = labels[b];
  int slot = atomicAdd(&bcnt[lb], 1);
  if (slot < BCAP) { bidx[lb * BCAP + slot] = b; bp[lb * BCAP + slot] = p; }
  float v = -logf(p + 1e-8f);
#pragma unroll
  for (int msk = 1; msk < 64; msk <<= 1) v += __shfl_xor(v, msk);
  if ((threadIdx.x & 63) == 0) wred[threadIdx.x >> 6] = v;
  __syncthreads();
  if (threadIdx.x == 0)
    sdc_partial[blockIdx.x] = wred[0] + wred[1] + wred[2] + wred[3];
}

// ---------------- mstep: one block per class, direct bucket gather.
// Block 0 additionally finalizes the scalar loss.
__global__ __launch_bounds__(256) void mstep_kernel(
    const float* __restrict__ features,
    const float* __restrict__ centers,
    const int* __restrict__ bcnt, const int* __restrict__ bidx,
    const float* __restrict__ bp,
    const float* __restrict__ ce_partial, const float* __restrict__ sdc_partial,
    float* __restrict__ out_loss, float* __restrict__ out_centers) {
  const int c = blockIdx.x;
  const int t = threadIdx.x;
  if (c == 0) {
    __shared__ float red[256];
    float s = 0.f;
    for (int i = t; i < CE_BLOCKS; i += 256) s += ce_partial[i];
    float s2 = 0.f;
    for (int i = t; i < 64; i += 256) s2 += sdc_partial[i];
    red[t] = s + 0.1f * s2;
    __syncthreads();
    for (int off = 128; off > 0; off >>= 1) {
      if (t < off) red[t] += red[t + off];
      __syncthreads();
    }
    if (t == 0) out_loss[0] = red[0] * (1.0f / 16384.0f);
  }
  int n = bcnt[c];
  if (n > BCAP) n = BCAP;
  float a0 = 0.f, a1 = 0.f, a2 = 0.f, ws = 0.f;
  int j = 0;
  for (; j + 2 <= n; j += 2) {
    int b0 = bidx[c * BCAP + j], b1 = bidx[c * BCAP + j + 1];
    float p0 = bp[c * BCAP + j], p1 = bp[c * BCAP + j + 1];
    const float* f0 = features + (size_t)b0 * FDIM;
    const float* f1 = features + (size_t)b1 * FDIM;
    float x00 = f0[t], x01 = f0[t + 256], x02 = f0[t + 512];
    float x10 = f1[t], x11 = f1[t + 256], x12 = f1[t + 512];
    a0 += p0 * x00 + p1 * x10;
    a1 += p0 * x01 + p1 * x11;
    a2 += p0 * x02 + p1 * x12;
    ws += p0 + p1;
  }
  if (j < n) {
    int b0 = bidx[c * BCAP + j];
    float p0 = bp[c * BCAP + j];
    const float* f0 = features + (size_t)b0 * FDIM;
    a0 += p0 * f0[t]; a1 += p0 * f0[t + 256]; a2 += p0 * f0[t + 512];
    ws += p0;
  }
  const float* crow = centers + (size_t)c * FDIM;
  float c0 = crow[t], c1 = crow[t + 256], c2 = crow[t + 512];
  size_t o = (size_t)c * FDIM + t;
  if (ws > 0.f) {
    float inv = 0.1f / (ws + 1e-8f);
    out_centers[o]       = 0.9f * c0 + a0 * inv;
    out_centers[o + 256] = 0.9f * c1 + a1 * inv;
    out_centers[o + 512] = 0.9f * c2 + a2 * inv;
  } else {
    out_centers[o]       = c0;
    out_centers[o + 256] = c1;
    out_centers[o + 512] = c2;
  }
}

extern "C" void kernel_launch(void* const* d_in, const int* in_sizes, int n_in,
                              void* d_out, int out_size, void* d_ws, size_t ws_size,
                              hipStream_t stream) {
  const float* outputs  = (const float*)d_in[0];
  const int*   labels   = (const int*)d_in[1];
  const float* features = (const float*)d_in[2];
  const float* centers  = (const float*)d_in[3];
  float* out = (float*)d_out;

  char* ws = (char*)d_ws;
  float* ztrue       = (float*)(ws);                          // 64 KB
  float* ce_partial  = (float*)(ws + (64 << 10));             // 16 KB
  float* sdc_partial = (float*)(ws + (80 << 10));             // 1 KB
  int*   bcnt        = (int*)(ws + (84 << 10));               // 4 KB
  float* pm          = (float*)(ws + (88 << 10));             // 512 KB
  float* psv         = (float*)(ws + (600 << 10));            // 512 KB
  unsigned short* cbf = (unsigned short*)(ws + (1112 << 10)); // 1.5 MB
  unsigned short* fbf = (unsigned short*)(ws + (2648 << 10)); // 24 MB
  // buckets overlay fbf (dead after gemm; written in combine, read in mstep)
  int*   bidx        = (int*)(ws + (2648 << 10));             // 512 KB
  float* bp          = (float*)(ws + (3160 << 10));           // 512 KB

  prep_kernel<<<CVT_BLOCKS + CE_BLOCKS, 256, 0, stream>>>(
      outputs, labels, features, centers, fbf, cbf, ce_partial);
  gemm_stats_kernel<<<2048, 256, 0, stream>>>(fbf, cbf, labels, pm, psv, ztrue, bcnt);
  combine_kernel<<<B_ROWS / 256, 256, 0, stream>>>(pm, psv, ztrue, labels,
                                                   bcnt, bidx, bp, sdc_partial);
  mstep_kernel<<<NCLS, 256, 0, stream>>>(features, centers, bcnt, bidx, bp,
                                         ce_partial, sdc_partial, out, out + 1);
}